// Round 3
// baseline (23886.934 us; speedup 1.0000x reference)
//
#include <hip/hip_runtime.h>

#define UNITS 65
#define SEQ   8192
#define BATCH 50

__device__ __forceinline__ float frcp(float x){ return __builtin_amdgcn_rcpf(x); }
__device__ __forceinline__ float fsigmoid(float x){ return frcp(1.0f + __expf(-x)); }
__device__ __forceinline__ float ftanh(float x){
    float e2 = __expf(2.0f * x);
    return 1.0f - 2.0f * frcp(e2 + 1.0f);
}

// DPP helpers (VALU pipe, no LDS traffic)
template<int CTRL>
__device__ __forceinline__ float dppadd(float x){
    int t = __builtin_amdgcn_update_dpp(0, __float_as_int(x), CTRL, 0xF, 0xF, true);
    return x + __int_as_float(t);
}
template<int CTRL>
__device__ __forceinline__ float dppmov(float x){
    int t = __builtin_amdgcn_update_dpp(0, __float_as_int(x), CTRL, 0xF, 0xF, true);
    return __int_as_float(t);
}
// sum over each quad; every lane of the quad gets the full sum
__device__ __forceinline__ float red4_all(float x){
    x = dppadd<0xB1>(x);   // quad_perm [1,0,3,2]
    x = dppadd<0x4E>(x);   // quad_perm [2,3,0,1]
    return x;
}
// 16-lane row sum; row total lands in lane (16*row + 15)
__device__ __forceinline__ float red16_lane15(float x){
    x = dppadd<0x111>(x);  // row_shr:1
    x = dppadd<0x112>(x);  // row_shr:2
    x = dppadd<0x114>(x);  // row_shr:4
    x = dppadd<0x118>(x);  // row_shr:8
    return x;
}
// barrier WITHOUT vmcnt drain (LDS ordering only) — globals here are block-private
__device__ __forceinline__ void bar_lds(){
    asm volatile("s_waitcnt lgkmcnt(0)\n\ts_barrier" ::: "memory");
}
__device__ __forceinline__ float rdlane(float v, int l){
    return __int_as_float(__builtin_amdgcn_readlane(__float_as_int(v), l));
}

// v layout: k in [0,130): k<65 -> in[k], k>=65 -> h[k-65]; 4 chunks at stride 36
// (chunks of 32,32,32,34; pads zeroed once and never written)
__device__ __forceinline__ int inpos(int k){
    int q = k >> 5; if (q > 3) q = 3;
    return q * 36 + (k - (q << 5));
}
// row k of concatenated [W;U] (K=130), column c
__device__ __forceinline__ float wrow(const float* W, const float* U, int k, int c){
    return (k < 65) ? W[k * 260 + c] : U[(k - 65) * 260 + c];
}

// ---------------------------------------------------------------------------
// Layer-pipelined 3-stack LSTM, TWO batch elements per block.
// 512 threads = 8 waves = 2 waves/SIMD: waves 0-3 -> element 2e, waves 4-7 ->
// element 2e+1. The two halves are independent dataflows sharing the block
// barrier; when one wave stalls (LDS latency, DPP/exp chains) the co-resident
// wave from the other element issues -> latency overlap on every SIMD.
// Pipeline step s computes, CONCURRENTLY (independent by dataflow):
//   layer0 @ t=s, layer1 @ t=s-1, layer2 @ t=s-2 (-> out row t=s-2)
// Unit 64 of layer (wave4-1) is computed IN-WAVE by waves4 1..3 (red16 +
// readlane) -> ONE barrier per step.
// ---------------------------------------------------------------------------

// Phase B for one layer's regular units. Writer lane (kq==3) commits state and
// performs WRITES (uses hn_).
#define LAYERB(aI, aF, aG, aO, CST, ...) do {                                  \
    float rI_ = red4_all(aI), rF_ = red4_all(aF);                              \
    float rG_ = red4_all(aG), rO_ = red4_all(aO);                              \
    float z_ = ((kq == 0) ? rI_ : (kq == 1) ? rF_ : (kq == 2) ? rG_ : rO_) + breg; \
    float sg_ = frcp(1.0f + __expf(-sk * z_));                                 \
    float g_  = fmaf(sk, sg_, dk);                                             \
    float gi_ = dppmov<0x00>(g_);                                              \
    float gf_ = dppmov<0x55>(g_);                                              \
    float gg_ = dppmov<0xAA>(g_);                                              \
    float cn_ = fmaf(gf_, CST, gi_ * gg_);                                     \
    float hn_ = g_ * ftanh(cn_);                                               \
    if (wr) { CST = cn_; __VA_ARGS__; }                                        \
} while (0)

#define STEP(L0, L1, L2) do {                                                  \
    const float* __restrict__ vbase = &vbuf[eh][cur][0][0];                    \
    float*       __restrict__ nbase = &vbuf[eh][cur ^ 1][0][0];                \
    /* issue x prefetch early; consumed next step (>=1 step of slack) */       \
    float xq1 = 0.0f, ex1 = 0.0f;                                              \
    if (L0) {                                                                  \
        const int tl_ = (s + 2 < SEQ) ? (s + 2) : (SEQ - 1);                   \
        if (wr) xq1 = xrow[(size_t)tl_ * UNITS + j];                           \
        if (wave4 == 1 && lane == 0) ex1 = xrow[(size_t)tl_ * UNITS + 64];     \
    }                                                                          \
    /* unit-64 operands (layer ml; wave4==0 computes a discarded duplicate) */ \
    const float* vm_ = vbase + ml * 144;                                       \
    float4 uA_ = *(const float4*)(vm_ + p64);                                  \
    float4 uB_ = *(const float4*)(vm_ + p64 + 4);                              \
    float  uex_ = (i64 < 2) ? vm_[140 + i64] : 0.0f;                           \
    /* phase A: fused LDS-load + 12 interleaved FMA chains (small live set) */ \
    const float* vp0_ = vbase + kq * 36;                                       \
    const float* vp1_ = vbase + 144 + kq * 36;                                 \
    const float* vp2_ = vbase + 288 + kq * 36;                                 \
    float aI0=0,aF0=0,aG0=0,aO0=0, aI1=0,aF1=0,aG1=0,aO1=0,                    \
          aI2=0,aF2=0,aG2=0,aO2=0;                                             \
    _Pragma("unroll")                                                          \
    for (int q8_ = 0; q8_ < 8; ++q8_) {                                        \
        float4 f0_, f1_, f2_;                                                  \
        if (L0) f0_ = *(const float4*)(vp0_ + 4 * q8_);                        \
        if (L1) f1_ = *(const float4*)(vp1_ + 4 * q8_);                        \
        if (L2) f2_ = *(const float4*)(vp2_ + 4 * q8_);                        \
        _Pragma("unroll")                                                      \
        for (int r_ = 0; r_ < 4; ++r_) {                                       \
            const int kk = 4 * q8_ + r_;                                       \
            if (L0) { float s0_ = (&f0_.x)[r_];                                \
                aI0=fmaf(s0_,wI[kk],aI0); aF0=fmaf(s0_,wF[kk],aF0);            \
                aG0=fmaf(s0_,wG[kk],aG0); aO0=fmaf(s0_,wO[kk],aO0); }          \
            if (L1) { float s1_ = (&f1_.x)[r_];                                \
                aI1=fmaf(s1_,wI[kk],aI1); aF1=fmaf(s1_,wF[kk],aF1);            \
                aG1=fmaf(s1_,wG[kk],aG1); aO1=fmaf(s1_,wO[kk],aO1); }          \
            if (L2) { float s2_ = (&f2_.x)[r_];                                \
                aI2=fmaf(s2_,wI[kk],aI2); aF2=fmaf(s2_,wF[kk],aF2);            \
                aG2=fmaf(s2_,wG[kk],aG2); aO2=fmaf(s2_,wO[kk],aO2); }          \
        }                                                                      \
    }                                                                          \
    {   /* tail kk = 32,33 */                                                  \
        float2 t0_, t1_, t2_;                                                  \
        if (L0) t0_ = *(const float2*)(vp0_ + 32);                             \
        if (L1) t1_ = *(const float2*)(vp1_ + 32);                             \
        if (L2) t2_ = *(const float2*)(vp2_ + 32);                             \
        _Pragma("unroll")                                                      \
        for (int r_ = 0; r_ < 2; ++r_) {                                       \
            const int kk = 32 + r_;                                            \
            if (L0) { float s0_ = (&t0_.x)[r_];                                \
                aI0=fmaf(s0_,wI[kk],aI0); aF0=fmaf(s0_,wF[kk],aF0);            \
                aG0=fmaf(s0_,wG[kk],aG0); aO0=fmaf(s0_,wO[kk],aO0); }          \
            if (L1) { float s1_ = (&t1_.x)[r_];                                \
                aI1=fmaf(s1_,wI[kk],aI1); aF1=fmaf(s1_,wF[kk],aF1);            \
                aG1=fmaf(s1_,wG[kk],aG1); aO1=fmaf(s1_,wO[kk],aO1); }          \
            if (L2) { float s2_ = (&t2_.x)[r_];                                \
                aI2=fmaf(s2_,wI[kk],aI2); aF2=fmaf(s2_,wF[kk],aF2);            \
                aG2=fmaf(s2_,wG[kk],aG2); aO2=fmaf(s2_,wO[kk],aO2); }          \
        }                                                                      \
    }                                                                          \
    /* unit-64 dot (9 MACs/lane) + in-wave row reduce */                       \
    float a64_ = uA_.x * w64[0];                                               \
    a64_ = fmaf(uA_.y, w64[1], a64_); a64_ = fmaf(uA_.z, w64[2], a64_);        \
    a64_ = fmaf(uA_.w, w64[3], a64_); a64_ = fmaf(uB_.x, w64[4], a64_);        \
    a64_ = fmaf(uB_.y, w64[5], a64_); a64_ = fmaf(uB_.z, w64[6], a64_);        \
    a64_ = fmaf(uB_.w, w64[7], a64_); a64_ = fmaf(uex_, w64x, a64_);           \
    a64_ = red16_lane15(a64_);                                                 \
    /* phase B per layer + vn writes */                                        \
    if (L0) LAYERB(aI0, aF0, aG0, aO0, c1,                                     \
                   nbase[ipH] = hn_; nbase[144 + ipI] = hn_);                  \
    if (L1) LAYERB(aI1, aF1, aG1, aO1, c2,                                     \
                   nbase[144 + ipH] = hn_; nbase[288 + ipI] = hn_);            \
    if (L2) LAYERB(aI2, aF2, aG2, aO2, c3,                                     \
                   nbase[288 + ipH] = hn_;                                     \
                   orow[(size_t)(s - 2) * UNITS + j] = hn_);                   \
    if (L0) { if (wr) { nbase[ipI] = xq0; xq0 = xq1; } }                       \
    /* unit-64 phase B: wave-uniform via readlane */                           \
    {                                                                          \
        const bool act64_ = (wave4 == 1) ? (bool)(L0)                          \
                          : (wave4 == 2) ? (bool)(L1)                          \
                          : (wave4 == 3) ? (bool)(L2) : false;                 \
        float zi_ = rdlane(a64_, 15) + b64i;                                   \
        float zf_ = rdlane(a64_, 31) + b64f;                                   \
        float zg_ = rdlane(a64_, 47) + b64g;                                   \
        float zo_ = rdlane(a64_, 63) + b64o;                                   \
        float gi4_ = fsigmoid(zi_), gf4_ = fsigmoid(zf_);                      \
        float gg4_ = ftanh(zg_),    go4_ = fsigmoid(zo_);                      \
        float cn64_ = fmaf(gf4_, c64, gi4_ * gg4_);                            \
        float hn64_ = go4_ * ftanh(cn64_);                                     \
        if (act64_) {                                                          \
            c64 = cn64_;                                                       \
            if (lane == 0) {                                                   \
                nbase[ml * 144 + 141] = hn64_;                                 \
                if (wave4 <= 2) nbase[wave4 * 144 + 72] = hn64_;               \
                else orow[(size_t)(s - 2) * UNITS + 64] = hn64_;               \
            }                                                                  \
            if (wave4 == 1) { if (lane == 0) nbase[72] = ex0; ex0 = ex1; }     \
        }                                                                      \
    }                                                                          \
    cur ^= 1;                                                                  \
    bar_lds();                                                                 \
} while (0)

// One block per TWO batch elements. 512 threads = 8 waves (2 waves/SIMD).
// eh = wave>>2 selects the element half; wave4 = wave&3 is the old wave id.
// lane = jl*4 + kq: unit j = wave4*16 + jl, K-chunk kq (0..3).
__global__ __launch_bounds__(512, 2)
void lstm3_kernel(const float* __restrict__ x, const float* __restrict__ W,
                  const float* __restrict__ U, const float* __restrict__ b,
                  float* __restrict__ out)
{
    const int tid   = threadIdx.x;
    const int wave  = tid >> 6, lane = tid & 63;
    const int eh    = wave >> 2, wave4 = wave & 3;
    const int e     = blockIdx.x * 2 + eh;
    const int kq    = lane & 3, jl = lane >> 2;
    const int j     = wave4 * 16 + jl;
    const bool wr   = (kq == 3);

    // [elem][parity][layer][144]: per-layer v = [input(65) | h(65)] chunked
    __shared__ __attribute__((aligned(16))) float vbuf[2][2][3][144];

    // ---- per-thread weights (K-chunk x 4 gates); kk>=32 for kq<3 hits v-pad zeros ----
    float wI[34], wF[34], wG[34], wO[34];
    #pragma unroll
    for (int kk = 0; kk < 34; ++kk) {
        int k = kq * 32 + kk;                 // <= 129 always
        wI[kk] = wrow(W, U, k, j);
        wF[kk] = wrow(W, U, k, 65  + j);
        wG[kk] = wrow(W, U, k, 130 + j);
        wO[kk] = wrow(W, U, k, 195 + j);
    }
    const float breg = b[kq * 65 + j];
    const float sk   = (kq == 2) ? 2.0f : 1.0f;   // g-gate: tanh(z) = 2*sigmoid(2z)-1
    const float dk   = 1.0f - sk;

    // unit-64 in-wave split: gate g64 = lane>>4, K-slice i64 = lane&15 (8 elems + rem)
    const int i64 = lane & 15, g64 = lane >> 4;
    const int p64 = (i64 >> 2) * 36 + 8 * (i64 & 3);  // inpos(8*i64), contiguous 8
    float w64[8], w64x;
    {
        const int c64 = g64 * 65 + 64;
        #pragma unroll
        for (int r = 0; r < 8; ++r) w64[r] = wrow(W, U, 8 * i64 + r, c64);
        w64x = (i64 < 2) ? wrow(W, U, 128 + i64, c64) : 0.0f;
    }
    const float b64i = b[64], b64f = b[129], b64g = b[194], b64o = b[259];
    const int ml = (wave4 == 0) ? 0 : wave4 - 1;   // unit-64 layer owned by this wave

    float c1 = 0, c2 = 0, c3 = 0, c64 = 0;         // cell states

    const float* xrow = x   + (size_t)e * SEQ * UNITS;
    float*       orow = out + (size_t)e * SEQ * UNITS;
    const int ipI = inpos(j), ipH = inpos(65 + j);

    // ---- init: zero LDS (pads + h-parts must be 0), then v0.in = x(0) ----
    for (int i = tid; i < 2 * 2 * 3 * 144; i += 512) ((float*)&vbuf[0][0][0][0])[i] = 0.0f;
    __syncthreads();
    if (wr)  vbuf[eh][0][0][ipI] = xrow[j];
    if (wave4 == 1 && lane == 0) vbuf[eh][0][0][72] = xrow[64];
    __syncthreads();

    // x prefetch: xq0 holds x(s+1) value at end of step s
    float xq0 = 0, ex0 = 0;
    if (wr) xq0 = xrow[UNITS + j];
    if (wave4 == 1 && lane == 0) ex0 = xrow[UNITS + 64];

    int cur = 0;
    int s = 0;
    STEP(1, 0, 0); ++s;                         // s=0: layer0 only
    STEP(1, 1, 0); ++s;                         // s=1: layers 0,1
    for (; s < SEQ; ++s) { STEP(1, 1, 1); }     // s=2..SEQ-1: all layers
    STEP(0, 1, 1); ++s;                         // s=SEQ: layers 1,2
    STEP(0, 0, 1);                              // s=SEQ+1: layer 2 drains
}

// Dense head, in place on d_out: out_row = row @ Wd + bd. One thread per row.
__global__ __launch_bounds__(256)
void dense_kernel(float* __restrict__ io,
                  const float* __restrict__ Wd,
                  const float* __restrict__ bd)
{
    __shared__ __attribute__((aligned(16))) float wS[65 * 68];
    __shared__ float bS[65];
    for (int i = threadIdx.x; i < 65 * 65; i += 256) {
        int r = i / 65, c = i - r * 65;
        wS[r * 68 + c] = Wd[i];
    }
    if (threadIdx.x < 65) bS[threadIdx.x] = bd[threadIdx.x];
    __syncthreads();

    const size_t row  = (size_t)blockIdx.x * 256 + threadIdx.x;
    const size_t base = row * 65;

    float r[65];
    #pragma unroll
    for (int k = 0; k < 65; ++k) r[k] = io[base + k];

    for (int ct = 0; ct < 16; ++ct) {
        const int c = ct * 4;
        float a0 = bS[c], a1 = bS[c + 1], a2 = bS[c + 2], a3 = bS[c + 3];
        #pragma unroll
        for (int k = 0; k < 65; ++k) {
            const float4 wv = *reinterpret_cast<const float4*>(&wS[k * 68 + c]);
            a0 += r[k] * wv.x;
            a1 += r[k] * wv.y;
            a2 += r[k] * wv.z;
            a3 += r[k] * wv.w;
        }
        io[base + c]     = a0;
        io[base + c + 1] = a1;
        io[base + c + 2] = a2;
        io[base + c + 3] = a3;
    }
    float a = bS[64];
    #pragma unroll
    for (int k = 0; k < 65; ++k) a += r[k] * wS[k * 68 + 64];
    io[base + 64] = a;
}

extern "C" void kernel_launch(void* const* d_in, const int* in_sizes, int n_in,
                              void* d_out, int out_size, void* d_ws, size_t ws_size,
                              hipStream_t stream)
{
    const float* x  = (const float*)d_in[0];
    const float* W  = (const float*)d_in[1];
    const float* U  = (const float*)d_in[2];
    const float* b  = (const float*)d_in[3];
    const float* Wd = (const float*)d_in[4];
    const float* bd = (const float*)d_in[5];
    float* out = (float*)d_out;

    hipLaunchKernelGGL(lstm3_kernel, dim3(BATCH / 2), dim3(512), 0, stream, x, W, U, b, out);
    hipLaunchKernelGGL(dense_kernel, dim3(1600), dim3(256), 0, stream, out, Wd, bd);
}

// Round 4
// 14508.379 us; speedup vs baseline: 1.6464x; 1.6464x over previous
//
#include <hip/hip_runtime.h>

#define UNITS 65
#define SEQ   8192
#define BATCH 50

__device__ __forceinline__ float frcp(float x){ return __builtin_amdgcn_rcpf(x); }
__device__ __forceinline__ float fsigmoid(float x){ return frcp(1.0f + __expf(-x)); }
__device__ __forceinline__ float ftanh(float x){
    float e2 = __expf(2.0f * x);
    return 1.0f - 2.0f * frcp(e2 + 1.0f);
}

// DPP helpers (VALU pipe, no LDS traffic)
template<int CTRL>
__device__ __forceinline__ float dppadd(float x){
    int t = __builtin_amdgcn_update_dpp(0, __float_as_int(x), CTRL, 0xF, 0xF, true);
    return x + __int_as_float(t);
}
template<int CTRL>
__device__ __forceinline__ float dppmov(float x){
    int t = __builtin_amdgcn_update_dpp(0, __float_as_int(x), CTRL, 0xF, 0xF, true);
    return __int_as_float(t);
}
// sum over each quad; every lane of the quad gets the full sum
__device__ __forceinline__ float red4_all(float x){
    x = dppadd<0xB1>(x);   // quad_perm [1,0,3,2]
    x = dppadd<0x4E>(x);   // quad_perm [2,3,0,1]
    return x;
}
// add the value from lane^4 (BitMode swizzle: xor=4, and=0x1F)
__device__ __forceinline__ float swzadd_xor4(float x){
    int t = __builtin_amdgcn_ds_swizzle(__float_as_int(x), 0x101F);
    return x + __int_as_float(t);
}
// sum over each aligned 8-lane group; every lane gets the full sum
__device__ __forceinline__ float red8_all(float x){
    return swzadd_xor4(red4_all(x));
}
// 16-lane row sum; row total lands in lane (16*row + 15)
__device__ __forceinline__ float red16_lane15(float x){
    x = dppadd<0x111>(x);  // row_shr:1
    x = dppadd<0x112>(x);  // row_shr:2
    x = dppadd<0x114>(x);  // row_shr:4
    x = dppadd<0x118>(x);  // row_shr:8
    return x;
}
// barrier WITHOUT vmcnt drain (LDS ordering only) — globals here are block-private
__device__ __forceinline__ void bar_lds(){
    asm volatile("s_waitcnt lgkmcnt(0)\n\ts_barrier" ::: "memory");
}
__device__ __forceinline__ float rdlane(float v, int l){
    return __int_as_float(__builtin_amdgcn_readlane(__float_as_int(v), l));
}

// v layout: k in [0,130): k<65 -> in[k], k>=65 -> h[k-65].
// 8 chunks of 16 k-values (last chunk 18) at stride 20 floats (80 B, 16B-aligned).
// pads zeroed once and never written. Per-layer v buffer = 160 floats.
__device__ __forceinline__ int inpos8(int k){
    return (k < 112) ? ((k >> 4) * 20 + (k & 15)) : (140 + (k - 112));
}
// row k of concatenated [W;U] (K=130), column c
__device__ __forceinline__ float wrow(const float* W, const float* U, int k, int c){
    return (k < 65) ? W[k * 260 + c] : U[(k - 65) * 260 + c];
}

// ---------------------------------------------------------------------------
// Layer-pipelined 3-stack LSTM, ONE element per block, 8 waves = 2 waves/SIMD.
// Each wave owns 8 units (j = wave*8 + ul) for ALL THREE layers; lane =
// ul*8 + k8 with k8 an 8-way K-split (16..18 k each). Halved per-wave FMA
// chains + two co-resident waves per SIMD hide the latency that dominated the
// 1-wave/SIMD version (72% stall measured). Pipeline step s computes,
// concurrently: layer0@t=s, layer1@t=s-1, layer2@t=s-2 (-> out row s-2).
// Unit 64 of layer (wave-1) is computed in-wave by waves 1..3 (red16 +
// readlane). ONE barrier per step; t-loop unrolled x2 so LDS bases fold.
// ---------------------------------------------------------------------------

// Phase B for one layer's regular units. Writer lane (k8==7) commits state and
// performs WRITES (uses hn_).
#define LAYERB(aI, aF, aG, aO, CST, ...) do {                                  \
    float rI_ = red8_all(aI), rF_ = red8_all(aF);                              \
    float rG_ = red8_all(aG), rO_ = red8_all(aO);                              \
    float z_ = ((gate == 0) ? rI_ : (gate == 1) ? rF_ : (gate == 2) ? rG_ : rO_) + breg; \
    float sg_ = frcp(1.0f + __expf(-sk * z_));                                 \
    float g_  = fmaf(sk, sg_, dk);                                             \
    float gi_ = dppmov<0x00>(g_);                                              \
    float gf_ = dppmov<0x55>(g_);                                              \
    float gg_ = dppmov<0xAA>(g_);                                              \
    float cn_ = fmaf(gf_, CST, gi_ * gg_);                                     \
    float hn_ = g_ * ftanh(cn_);                                               \
    if (wr) { CST = cn_; __VA_ARGS__; }                                        \
} while (0)

#define STEP(L0, L1, L2, VB, NB) do {                                          \
    const float* __restrict__ vbase = (VB);                                    \
    float*       __restrict__ nbase = (NB);                                    \
    /* x prefetch issued early; consumed next step (>=1 step of slack) */      \
    float xq1 = 0.0f, ex1 = 0.0f;                                              \
    if (L0) {                                                                  \
        const int tl_ = (s + 2 < SEQ) ? (s + 2) : (SEQ - 1);                   \
        if (wr) xq1 = xrow[(size_t)tl_ * UNITS + j];                           \
        if (wave == 1 && lane == 0) ex1 = xrow[(size_t)tl_ * UNITS + 64];      \
    }                                                                          \
    /* phase A: fused LDS-load + 12 interleaved FMA chains, 18-deep */         \
    const float* vp0_ = vbase + k8 * 20;                                       \
    const float* vp1_ = vbase + 160 + k8 * 20;                                 \
    const float* vp2_ = vbase + 320 + k8 * 20;                                 \
    float aI0=0,aF0=0,aG0=0,aO0=0, aI1=0,aF1=0,aG1=0,aO1=0,                    \
          aI2=0,aF2=0,aG2=0,aO2=0;                                             \
    _Pragma("unroll")                                                          \
    for (int q4_ = 0; q4_ < 4; ++q4_) {                                        \
        float4 f0_, f1_, f2_;                                                  \
        if (L0) f0_ = *(const float4*)(vp0_ + 4 * q4_);                        \
        if (L1) f1_ = *(const float4*)(vp1_ + 4 * q4_);                        \
        if (L2) f2_ = *(const float4*)(vp2_ + 4 * q4_);                        \
        _Pragma("unroll")                                                      \
        for (int r_ = 0; r_ < 4; ++r_) {                                       \
            const int kk = 4 * q4_ + r_;                                       \
            if (L0) { float s0_ = (&f0_.x)[r_];                                \
                aI0=fmaf(s0_,wI[kk],aI0); aF0=fmaf(s0_,wF[kk],aF0);            \
                aG0=fmaf(s0_,wG[kk],aG0); aO0=fmaf(s0_,wO[kk],aO0); }          \
            if (L1) { float s1_ = (&f1_.x)[r_];                                \
                aI1=fmaf(s1_,wI[kk],aI1); aF1=fmaf(s1_,wF[kk],aF1);            \
                aG1=fmaf(s1_,wG[kk],aG1); aO1=fmaf(s1_,wO[kk],aO1); }          \
            if (L2) { float s2_ = (&f2_.x)[r_];                                \
                aI2=fmaf(s2_,wI[kk],aI2); aF2=fmaf(s2_,wF[kk],aF2);            \
                aG2=fmaf(s2_,wG[kk],aG2); aO2=fmaf(s2_,wO[kk],aO2); }          \
        }                                                                      \
    }                                                                          \
    {   /* tail kk = 16,17 (pads zero for k8<7; weights also zeroed) */        \
        float2 t0_, t1_, t2_;                                                  \
        if (L0) t0_ = *(const float2*)(vp0_ + 16);                             \
        if (L1) t1_ = *(const float2*)(vp1_ + 16);                             \
        if (L2) t2_ = *(const float2*)(vp2_ + 16);                             \
        _Pragma("unroll")                                                      \
        for (int r_ = 0; r_ < 2; ++r_) {                                       \
            const int kk = 16 + r_;                                            \
            if (L0) { float s0_ = (&t0_.x)[r_];                                \
                aI0=fmaf(s0_,wI[kk],aI0); aF0=fmaf(s0_,wF[kk],aF0);            \
                aG0=fmaf(s0_,wG[kk],aG0); aO0=fmaf(s0_,wO[kk],aO0); }          \
            if (L1) { float s1_ = (&t1_.x)[r_];                                \
                aI1=fmaf(s1_,wI[kk],aI1); aF1=fmaf(s1_,wF[kk],aF1);            \
                aG1=fmaf(s1_,wG[kk],aG1); aO1=fmaf(s1_,wO[kk],aO1); }          \
            if (L2) { float s2_ = (&t2_.x)[r_];                                \
                aI2=fmaf(s2_,wI[kk],aI2); aF2=fmaf(s2_,wF[kk],aF2);            \
                aG2=fmaf(s2_,wG[kk],aG2); aO2=fmaf(s2_,wO[kk],aO2); }          \
        }                                                                      \
    }                                                                          \
    /* unit-64 (only owner waves 1..3): 9-MAC dot + in-wave row reduce */      \
    const bool act64_ = (wave == 1) ? (bool)(L0)                               \
                      : (wave == 2) ? (bool)(L1)                               \
                      : (wave == 3) ? (bool)(L2) : false;                      \
    float a64_ = 0.0f;                                                         \
    if (act64_) {                                                              \
        const float* vm_ = vbase + ml * 160;                                   \
        float4 uA_ = *(const float4*)(vm_ + p64);                              \
        float4 uB_ = *(const float4*)(vm_ + p64 + 4);                          \
        float  uex_ = (i64 < 2) ? vm_[156 + i64] : 0.0f;                       \
        a64_ = uA_.x * w64[0];                                                 \
        a64_ = fmaf(uA_.y, w64[1], a64_); a64_ = fmaf(uA_.z, w64[2], a64_);    \
        a64_ = fmaf(uA_.w, w64[3], a64_); a64_ = fmaf(uB_.x, w64[4], a64_);    \
        a64_ = fmaf(uB_.y, w64[5], a64_); a64_ = fmaf(uB_.z, w64[6], a64_);    \
        a64_ = fmaf(uB_.w, w64[7], a64_); a64_ = fmaf(uex_, w64x, a64_);       \
        a64_ = red16_lane15(a64_);                                             \
    }                                                                          \
    /* phase B per layer + vn writes */                                        \
    if (L0) LAYERB(aI0, aF0, aG0, aO0, c1,                                     \
                   nbase[ipH] = hn_; nbase[160 + ipI] = hn_);                  \
    if (L1) LAYERB(aI1, aF1, aG1, aO1, c2,                                     \
                   nbase[160 + ipH] = hn_; nbase[320 + ipI] = hn_);            \
    if (L2) LAYERB(aI2, aF2, aG2, aO2, c3,                                     \
                   nbase[320 + ipH] = hn_;                                     \
                   orow[(size_t)(s - 2) * UNITS + j] = hn_);                   \
    if (L0) { if (wr) { nbase[ipI] = xq0; xq0 = xq1; } }                       \
    /* unit-64 phase B: wave-uniform via readlane */                           \
    if (act64_) {                                                              \
        float zi_ = rdlane(a64_, 15) + b64i;                                   \
        float zf_ = rdlane(a64_, 31) + b64f;                                   \
        float zg_ = rdlane(a64_, 47) + b64g;                                   \
        float zo_ = rdlane(a64_, 63) + b64o;                                   \
        float gi4_ = fsigmoid(zi_), gf4_ = fsigmoid(zf_);                      \
        float gg4_ = ftanh(zg_),    go4_ = fsigmoid(zo_);                      \
        float cn64_ = fmaf(gf4_, c64, gi4_ * gg4_);                            \
        float hn64_ = go4_ * ftanh(cn64_);                                     \
        c64 = cn64_;                                                           \
        if (lane == 0) {                                                       \
            nbase[ml * 160 + 157] = hn64_;                /* own h-slot 64 */  \
            if (wave <= 2) nbase[(ml + 1) * 160 + 80] = hn64_; /* next in */   \
            else orow[(size_t)(s - 2) * UNITS + 64] = hn64_;                   \
        }                                                                      \
        if (wave == 1) { if (lane == 0) nbase[80] = ex0; ex0 = ex1; }          \
    }                                                                          \
    bar_lds();                                                                 \
} while (0)

// One block per batch element. 512 threads = 8 waves = 2 waves/SIMD.
// lane = ul*8 + k8: unit j = wave*8 + ul (0..63), K-chunk k8 (0..7).
__global__ __launch_bounds__(512, 2)
void lstm3_kernel(const float* __restrict__ x, const float* __restrict__ W,
                  const float* __restrict__ U, const float* __restrict__ b,
                  float* __restrict__ out)
{
    const int e    = blockIdx.x;
    const int tid  = threadIdx.x;
    const int wave = tid >> 6, lane = tid & 63;
    const int k8   = lane & 7, ul = lane >> 3;
    const int j    = wave * 8 + ul;
    const int gate = k8 & 3;
    const bool wr  = (k8 == 7);

    // [parity][layer][160]: per-layer v = [input(65) | h(65)] in 8-chunk layout
    __shared__ __attribute__((aligned(16))) float vbuf[2][3][160];

    // ---- per-thread weights (K-chunk x 4 gates); invalid tail slots = 0 ----
    float wI[18], wF[18], wG[18], wO[18];
    #pragma unroll
    for (int kk = 0; kk < 18; ++kk) {
        const int  k   = 16 * k8 + kk;                // <= 129 when valid
        const bool val = (kk < 16) || (k8 == 7);
        wI[kk] = val ? wrow(W, U, k, j)       : 0.0f;
        wF[kk] = val ? wrow(W, U, k, 65  + j) : 0.0f;
        wG[kk] = val ? wrow(W, U, k, 130 + j) : 0.0f;
        wO[kk] = val ? wrow(W, U, k, 195 + j) : 0.0f;
    }
    const float breg = b[gate * 65 + j];
    const float sk   = (gate == 2) ? 2.0f : 1.0f;  // g-gate: tanh(z)=2*sig(2z)-1
    const float dk   = 1.0f - sk;

    // unit-64 in-wave split: gate g64 = lane>>4, K-slice i64 = lane&15 (8 k + rem)
    const int i64 = lane & 15, g64 = lane >> 4;
    const int p64 = (i64 >> 1) * 20 + 8 * (i64 & 1);  // inpos8(8*i64), contiguous 8
    float w64[8], w64x;
    {
        const int c64c = g64 * 65 + 64;
        #pragma unroll
        for (int r = 0; r < 8; ++r) w64[r] = wrow(W, U, 8 * i64 + r, c64c);
        w64x = (i64 < 2) ? wrow(W, U, 128 + i64, c64c) : 0.0f;
    }
    const float b64i = b[64], b64f = b[129], b64g = b[194], b64o = b[259];
    const int ml = (wave >= 1 && wave <= 3) ? (wave - 1) : 0;

    float c1 = 0, c2 = 0, c3 = 0, c64 = 0;         // cell states

    const float* xrow = x   + (size_t)e * SEQ * UNITS;
    float*       orow = out + (size_t)e * SEQ * UNITS;
    const int ipI = inpos8(j), ipH = inpos8(65 + j);

    // ---- init: zero LDS (pads + h-parts must be 0), then v0.in = x(0) ----
    for (int i = tid; i < 2 * 3 * 160; i += 512) ((float*)&vbuf[0][0][0])[i] = 0.0f;
    __syncthreads();
    if (wr)  vbuf[0][0][ipI] = xrow[j];
    if (wave == 1 && lane == 0) vbuf[0][0][80] = xrow[64];   // inpos8(64)=80
    __syncthreads();

    // x prefetch: xq0 holds x(s+1) value at end of step s
    float xq0 = 0, ex0 = 0;
    if (wr) xq0 = xrow[UNITS + j];
    if (wave == 1 && lane == 0) ex0 = xrow[UNITS + 64];

    float* const vb0 = &vbuf[0][0][0];
    float* const vb1 = &vbuf[1][0][0];
    int s = 0;
    STEP(1, 0, 0, vb0, vb1); ++s;               // s=0: layer0 only
    STEP(1, 1, 0, vb1, vb0); ++s;               // s=1: layers 0,1
    for (; s < SEQ - 1; ) {                     // s=2..SEQ-1 (8190 steps, even)
        STEP(1, 1, 1, vb0, vb1); ++s;
        STEP(1, 1, 1, vb1, vb0); ++s;
    }
    STEP(0, 1, 1, vb0, vb1); ++s;               // s=SEQ: layers 1,2
    STEP(0, 0, 1, vb1, vb0);                    // s=SEQ+1: layer 2 drains
}

// Dense head, in place on d_out: out_row = row @ Wd + bd. One thread per row.
__global__ __launch_bounds__(256)
void dense_kernel(float* __restrict__ io,
                  const float* __restrict__ Wd,
                  const float* __restrict__ bd)
{
    __shared__ __attribute__((aligned(16))) float wS[65 * 68];
    __shared__ float bS[65];
    for (int i = threadIdx.x; i < 65 * 65; i += 256) {
        int r = i / 65, c = i - r * 65;
        wS[r * 68 + c] = Wd[i];
    }
    if (threadIdx.x < 65) bS[threadIdx.x] = bd[threadIdx.x];
    __syncthreads();

    const size_t row  = (size_t)blockIdx.x * 256 + threadIdx.x;
    const size_t base = row * 65;

    float r[65];
    #pragma unroll
    for (int k = 0; k < 65; ++k) r[k] = io[base + k];

    for (int ct = 0; ct < 16; ++ct) {
        const int c = ct * 4;
        float a0 = bS[c], a1 = bS[c + 1], a2 = bS[c + 2], a3 = bS[c + 3];
        #pragma unroll
        for (int k = 0; k < 65; ++k) {
            const float4 wv = *reinterpret_cast<const float4*>(&wS[k * 68 + c]);
            a0 += r[k] * wv.x;
            a1 += r[k] * wv.y;
            a2 += r[k] * wv.z;
            a3 += r[k] * wv.w;
        }
        io[base + c]     = a0;
        io[base + c + 1] = a1;
        io[base + c + 2] = a2;
        io[base + c + 3] = a3;
    }
    float a = bS[64];
    #pragma unroll
    for (int k = 0; k < 65; ++k) a += r[k] * wS[k * 68 + 64];
    io[base + 64] = a;
}

extern "C" void kernel_launch(void* const* d_in, const int* in_sizes, int n_in,
                              void* d_out, int out_size, void* d_ws, size_t ws_size,
                              hipStream_t stream)
{
    const float* x  = (const float*)d_in[0];
    const float* W  = (const float*)d_in[1];
    const float* U  = (const float*)d_in[2];
    const float* b  = (const float*)d_in[3];
    const float* Wd = (const float*)d_in[4];
    const float* bd = (const float*)d_in[5];
    float* out = (float*)d_out;

    hipLaunchKernelGGL(lstm3_kernel, dim3(BATCH), dim3(512), 0, stream, x, W, U, b, out);
    hipLaunchKernelGGL(dense_kernel, dim3(1600), dim3(256), 0, stream, out, Wd, bd);
}